// Round 12
// baseline (206.005 us; speedup 1.0000x reference)
//
#include <hip/hip_runtime.h>
#include <math.h>

typedef float    floatx4 __attribute__((ext_vector_type(4)));
typedef _Float16 half8   __attribute__((ext_vector_type(8)));
typedef _Float16 half4v  __attribute__((ext_vector_type(4)));
typedef _Float16 half2v  __attribute__((ext_vector_type(2)));
typedef __fp16   fp16x2  __attribute__((ext_vector_type(2)));

constexpr int B    = 2;
constexpr int S    = 2048;
constexpr int NH   = 16;
constexpr int HD   = 64;
constexpr int DIM  = 1024;
constexpr int INNER = 1024;
constexpr int QKVN = 3072;
constexpr int NTOK = 4096;
constexpr float EPS = 1e-5f;
constexpr float MAX_SCALE = 10.0f;
constexpr float SCALE_LOG2E = 0.125f * 1.4426950408889634f;

#define MFMA32(a, b, c) __builtin_amdgcn_mfma_f32_16x16x32_f16((a), (b), (c), 0, 0, 0)

__device__ __forceinline__ half2v pkrtz(float a, float b) {
  fp16x2 t = __builtin_amdgcn_cvt_pkrtz(a, b);
  return __builtin_bit_cast(half2v, t);
}
__device__ __forceinline__ half2v hmax2(half2v a, half2v b) {
  return __builtin_elementwise_max(a, b);
}

// Direct global->LDS DMA, 16 B per lane (attn staging only; all GEMM
// DMA-staging variants measured WORSE than reg-prefetch: R1 157, R2/3 158,
// R4 162, R6 159 vs R0 152 us non-attn. Do not re-introduce in GEMM.
// R11's XCD-partitioned remap also regressed (201.5 -> 205.9): L3-resident
// operands make XCD locality tweaks neutral-to-negative on this chip.)
__device__ __forceinline__ void gl_lds16(const _Float16* g, _Float16* l) {
  __builtin_amdgcn_global_load_lds(
      (__attribute__((address_space(1))) void*)g,
      (__attribute__((address_space(3))) void*)l, 16, 0, 0);
}

// ---------------------------------------------------------------------------
// Fused prep: blockIdx [0,2048) fp32->fp16 convert of hs;
// [2048,2816) transpose w_qkv; [2816,3072) transpose w_out.
// ---------------------------------------------------------------------------
__device__ __forceinline__ void transpose_tile(const float* __restrict__ w,
                                               _Float16* __restrict__ wT,
                                               int K, int N, int k0, int n0,
                                               _Float16* T, int tid) {
#pragma unroll
  for (int i = 0; i < 4; ++i) {
    int id = tid + 256 * i;
    int r = id >> 4, c = id & 15;
    float4 v = *(const float4*)&w[(size_t)(k0 + r) * N + n0 + c * 4];
    half4v s; s[0] = (_Float16)v.x; s[1] = (_Float16)v.y;
    s[2] = (_Float16)v.z; s[3] = (_Float16)v.w;
    *(half4v*)&T[r * 72 + c * 4] = s;
  }
  __syncthreads();
#pragma unroll
  for (int i = 0; i < 2; ++i) {
    int id = tid + 256 * i;
    int n = id >> 3, cs = id & 7;
    half8 o;
#pragma unroll
    for (int jj = 0; jj < 8; ++jj) o[jj] = T[(cs * 8 + jj) * 72 + n];
    *(half8*)&wT[(size_t)(n0 + n) * K + k0 + cs * 8] = o;
  }
}

__global__ __launch_bounds__(256)
void prep_all(const float* __restrict__ hs, const float* __restrict__ w_qkv,
              const float* __restrict__ w_out, _Float16* __restrict__ hsb,
              _Float16* __restrict__ wqkvT, _Float16* __restrict__ woutT) {
  __shared__ _Float16 T[64 * 72];
  const int bx = blockIdx.x, tid = threadIdx.x;
  if (bx < 2048) {
    int id = bx * 256 + tid;
    const float4 a = ((const float4*)hs)[id * 2];
    const float4 b = ((const float4*)hs)[id * 2 + 1];
    half8 o;
    o[0] = (_Float16)a.x; o[1] = (_Float16)a.y; o[2] = (_Float16)a.z; o[3] = (_Float16)a.w;
    o[4] = (_Float16)b.x; o[5] = (_Float16)b.y; o[6] = (_Float16)b.z; o[7] = (_Float16)b.w;
    ((half8*)hsb)[id] = o;
  } else if (bx < 2816) {
    int id = bx - 2048;
    transpose_tile(w_qkv, wqkvT, DIM, QKVN, (id / 48) * 64, (id % 48) * 64, T, tid);
  } else {
    int id = bx - 2816;
    transpose_tile(w_out, woutT, INNER, DIM, (id / 16) * 64, (id % 16) * 64, T, tid);
  }
}

// ---------------------------------------------------------------------------
// fp16 MFMA GEMM, reg-prefetch staging (measured-best mechanism), BK=64,
// default block mapping (R11's XCD remap regressed — reverted).
// FUSE_V (R10): V-third blocks (n0 >= 2048) write accumulators DIRECTLY to
// vT in the attn fragment layout (byte-identical to post_all's old V-pass):
//   lane holds acc[i][j][r] = V[token tw = quad*4 + i*16 + r][d = j*16+l16]
//   -> vT tile position d*64 + quad*16 + i*4 + r (contiguous 32B per lane,j)
// This deletes the 8 MB qkvh-V write + 8 MB read.
// ---------------------------------------------------------------------------
template<int BN, bool OUT_F16, bool FUSE_V, typename OutT>
__global__ __launch_bounds__(256)
void gemm_bt(const _Float16* __restrict__ A, const _Float16* __restrict__ BT,
             const float* __restrict__ bias, OutT* __restrict__ C, int N, int K,
             _Float16* __restrict__ vt) {
  constexpr int NJ  = BN / 32;            // col-frags per wave
  constexpr int NSB = BN / 32;            // B staging slots per thread
  __shared__ _Float16 As[128 * 72];
  __shared__ _Float16 Bs[BN * 72];
  const int tid = threadIdx.x;
  const int wave = tid >> 6, lane = tid & 63, quad = lane >> 4, l16 = lane & 15;
  const int wm = wave >> 1, wn = wave & 1;
  const int m0 = blockIdx.y * 128, n0 = blockIdx.x * BN;

  // staging: thread covers rows r0+32s, k-cols [c0, c0+8) of the 64-wide slice
  const int r0 = tid >> 3;                // 0..31
  const int c0 = (tid & 7) * 8;           // 0..56
  const _Float16* Ap = A  + (size_t)(m0 + r0) * K + c0;
  const _Float16* Bp = BT + (size_t)(n0 + r0) * K + c0;

  half8 ar[4], br[NSB];
#pragma unroll
  for (int s = 0; s < 4; ++s) ar[s] = *(const half8*)(Ap + (size_t)(32 * s) * K);
#pragma unroll
  for (int s = 0; s < NSB; ++s) br[s] = *(const half8*)(Bp + (size_t)(32 * s) * K);

  floatx4 acc[4][NJ] = {};

  for (int k0 = 0; k0 < K; k0 += 64) {
    __syncthreads();
#pragma unroll
    for (int s = 0; s < 4; ++s) *(half8*)&As[(r0 + 32 * s) * 72 + c0] = ar[s];
#pragma unroll
    for (int s = 0; s < NSB; ++s) *(half8*)&Bs[(r0 + 32 * s) * 72 + c0] = br[s];
    if (k0 + 64 < K) {
#pragma unroll
      for (int s = 0; s < 4; ++s)
        ar[s] = *(const half8*)(Ap + (size_t)(32 * s) * K + k0 + 64);
#pragma unroll
      for (int s = 0; s < NSB; ++s)
        br[s] = *(const half8*)(Bp + (size_t)(32 * s) * K + k0 + 64);
    }
    __syncthreads();
#pragma unroll
    for (int ks = 0; ks < 2; ++ks) {
      half8 a[4], b[NJ];
#pragma unroll
      for (int i = 0; i < 4; ++i)
        a[i] = *(const half8*)&As[(wm * 64 + i * 16 + l16) * 72 + ks * 32 + quad * 8];
#pragma unroll
      for (int j = 0; j < NJ; ++j)
        b[j] = *(const half8*)&Bs[(wn * (BN / 2) + j * 16 + l16) * 72 + ks * 32 + quad * 8];
#pragma unroll
      for (int i = 0; i < 4; ++i)
#pragma unroll
        for (int j = 0; j < NJ; ++j)
          acc[i][j] = MFMA32(a[i], b[j], acc[i][j]);
    }
  }

  const int rb = m0 + wm * 64 + quad * 4;
  const int cb = n0 + wn * (BN / 2) + l16;

  if constexpr (FUSE_V) {
    if (n0 >= 2 * INNER) {
      // V block: write vT directly (attn fragment layout), skip qkvh.
      const int h  = ((n0 - 2 * INNER) >> 6) + wn;     // head (one per wave)
      const int bb = m0 >> 11;                          // batch
      const int kt = ((m0 & (S - 1)) >> 6) + wm;        // 64-token tile idx
      _Float16* orow = vt + ((size_t)(bb * NH + h) * 32 + kt) * (64 * 64);
#pragma unroll
      for (int j = 0; j < NJ; ++j) {
        const float bj = bias[cb + j * 16];
        const int d = j * 16 + l16;
#pragma unroll
        for (int i = 0; i < 4; ++i) {
          half4v o;
#pragma unroll
          for (int r = 0; r < 4; ++r) o[r] = (_Float16)(acc[i][j][r] + bj);
          *(half4v*)&orow[d * 64 + quad * 16 + i * 4] = o;
        }
      }
      return;
    }
  }

#pragma unroll
  for (int j = 0; j < NJ; ++j) {
    const float bj = bias[cb + j * 16];
#pragma unroll
    for (int i = 0; i < 4; ++i) {
#pragma unroll
      for (int r = 0; r < 4; ++r) {
        float v = acc[i][j][r] + bj;
        size_t idx2 = (size_t)(rb + i * 16 + r) * N + cb + j * 16;
        if constexpr (OUT_F16) C[idx2] = (_Float16)v; else C[idx2] = v;
      }
    }
  }
}

// ---------------------------------------------------------------------------
// Fused post (V-transpose lives in gemm1's epilogue since R10):
// 4096 blocks, per-token RMSNorm + rotary + hist-scale on q,k only.
// ---------------------------------------------------------------------------
__global__ __launch_bounds__(256)
void post_all(const _Float16* __restrict__ qkvh, const float* __restrict__ rot,
              const float* __restrict__ nqw, const float* __restrict__ nkw,
              const float* __restrict__ hks, const int* __restrict__ octx,
              _Float16* __restrict__ qo_, _Float16* __restrict__ ko_) {
  __shared__ float red[8];
  const int tid = threadIdx.x;
  const int token = blockIdx.x;
  const int b = token >> 11, spos = token & (S - 1);
  const _Float16* qrow = qkvh + (size_t)token * QKVN;
  const _Float16* krow = qrow + INNER;
  const float* r = rot + (size_t)token * (2 * HD);

  const int e0 = tid * 4;
  half4v qs = *(const half4v*)(qrow + e0);
  half4v ks = *(const half4v*)(krow + e0);
  float q4[4], k4[4];
#pragma unroll
  for (int i = 0; i < 4; ++i) { q4[i] = (float)qs[i]; k4[i] = (float)ks[i]; }

  float sq = 0.f, sk = 0.f;
#pragma unroll
  for (int i = 0; i < 4; ++i) { sq += q4[i] * q4[i]; sk += k4[i] * k4[i]; }
#pragma unroll
  for (int msk = 1; msk < 64; msk <<= 1) {
    sq += __shfl_xor(sq, msk);
    sk += __shfl_xor(sk, msk);
  }
  const int wv = tid >> 6;
  if ((tid & 63) == 0) { red[wv] = sq; red[4 + wv] = sk; }
  __syncthreads();
  sq = red[0] + red[1] + red[2] + red[3];
  sk = red[4] + red[5] + red[6] + red[7];

  const float qinv = 1.0f / sqrtf(sq * (1.0f / INNER) + EPS);
  const float kinv = 1.0f / sqrtf(sk * (1.0f / INNER) + EPS);

#pragma unroll
  for (int i = 0; i < 4; ++i) {
    q4[i] = q4[i] * qinv * nqw[e0 + i];
    k4[i] = k4[i] * kinv * nkw[e0 + i];
  }

  const int h = e0 >> 6, d0 = e0 & (HD - 1);
  const float c0 = r[d0],     s0 = r[HD + d0 + 1];
  const float c1 = r[d0 + 2], s1 = r[HD + d0 + 3];

  float qo[4], ko[4];
  qo[0] = q4[0] * c0 - q4[1] * s0;
  qo[1] = q4[0] * s0 + q4[1] * c0;
  qo[2] = q4[2] * c1 - q4[3] * s1;
  qo[3] = q4[2] * s1 + q4[3] * c1;
  ko[0] = k4[0] * c0 - k4[1] * s0;
  ko[1] = k4[0] * s0 + k4[1] * c0;
  ko[2] = k4[2] * c1 - k4[3] * s1;
  ko[3] = k4[2] * s1 + k4[3] * c1;

  const int hist = S - octx[0];
  if (hist > 0 && spos < hist) {
    const float sig = 1.0f / (1.0f + expf(-hks[h]));
    const float sc = 1.0f + sig * (MAX_SCALE - 1.0f);
#pragma unroll
    for (int i = 0; i < 4; ++i) ko[i] *= sc;
  }

  half4v qo4, ko4;
#pragma unroll
  for (int i = 0; i < 4; ++i) {
    qo4[i] = (_Float16)(qo[i] * SCALE_LOG2E);
    ko4[i] = (_Float16)ko[i];
  }
  const size_t obase = ((size_t)(b * NH + h) * S + spos) * HD + d0;
  *(half4v*)(qo_ + obase) = qo4;
  *(half4v*)(ko_ + obase) = ko4;
}

// ---------------------------------------------------------------------------
// MFMA flash attention — R7 version verbatim (measured best: ~51 us).
// 512 thr = 8 waves, 16 Q-rows/wave, 2 K-tiles per barrier with shared
// max-update, DMA staging with XOR source swizzle, defer-max, ones-MFMA
// row-sum, PV via 16x16x32, T5 setprio around MFMA clusters.
// ---------------------------------------------------------------------------
__global__ __launch_bounds__(512, 4)
void attn_mfma(const _Float16* __restrict__ qb, const _Float16* __restrict__ kb,
               const _Float16* __restrict__ vt, _Float16* __restrict__ attnb) {
  __shared__ _Float16 Kbuf[2][2][64 * 64];
  __shared__ _Float16 Vbuf[2][2][64 * 64];
  const int bh = blockIdx.x;
  const int b = bh >> 4, h = bh & 15;
  const int q0 = blockIdx.y * 128;
  const int tid = threadIdx.x;
  const int wave = tid >> 6, lane = tid & 63, quad = lane >> 4, l16 = lane & 15;
  const int rx = l16 & 7;

  const _Float16* qbh = qb + (size_t)bh * S * HD;
  const _Float16* kbh = kb + (size_t)bh * S * HD;
  const _Float16* vbh = vt + (size_t)bh * S * HD;

  half8 aq[2];
#pragma unroll
  for (int ks = 0; ks < 2; ++ks)
    aq[ks] = *(const half8*)&qbh[(size_t)(q0 + wave * 16 + l16) * HD + ks * 32 + quad * 8];

  const int srow = wave * 8 + (lane >> 3);
  const int soff = srow * 64 + (((lane & 7) ^ (srow & 7)) * 8);

  auto stage = [&](int p, int buf) {
    const _Float16* kt = kbh + (size_t)p * 8192;
    const _Float16* vp = vbh + (size_t)p * 8192;
    gl_lds16(kt + soff,        &Kbuf[buf][0][wave * 512]);
    gl_lds16(kt + 4096 + soff, &Kbuf[buf][1][wave * 512]);
    gl_lds16(vp + soff,        &Vbuf[buf][0][wave * 512]);
    gl_lds16(vp + 4096 + soff, &Vbuf[buf][1][wave * 512]);
  };

  stage(0, 0);
  __syncthreads();   // drains vmcnt(0): pair 0 resident

  floatx4 o16[4] = {};
  floatx4 lacc = {};                      // row-sums, same layout as o16 rows
  float mrow = -INFINITY;

  half8 ones8;
#pragma unroll
  for (int i = 0; i < 8; ++i) ones8[i] = (_Float16)1.f;

  auto compute_pair = [&](const _Float16* K0, const _Float16* K1,
                          const _Float16* V0, const _Float16* V1) {
    floatx4 scA[4] = {}, scB[4] = {};
    __builtin_amdgcn_s_setprio(1);
#pragma unroll
    for (int jj = 0; jj < 4; ++jj) {
#pragma unroll
      for (int ks = 0; ks < 2; ++ks) {
        const int co = (jj * 16 + l16) * 64 + (((ks * 4 + quad) ^ rx) * 8);
        half8 akA = *(const half8*)&K0[co];
        half8 akB = *(const half8*)&K1[co];
        scA[jj] = MFMA32(akA, aq[ks], scA[jj]);
        scB[jj] = MFMA32(akB, aq[ks], scB[jj]);
      }
    }
    __builtin_amdgcn_s_setprio(0);

    half2v phA[8], phB[8];
#pragma unroll
    for (int jj = 0; jj < 4; ++jj) {
      phA[jj * 2]     = pkrtz(scA[jj][0], scA[jj][1]);
      phA[jj * 2 + 1] = pkrtz(scA[jj][2], scA[jj][3]);
      phB[jj * 2]     = pkrtz(scB[jj][0], scB[jj][1]);
      phB[jj * 2 + 1] = pkrtz(scB[jj][2], scB[jj][3]);
    }
    half2v mA = hmax2(hmax2(hmax2(phA[0], phA[1]), hmax2(phA[2], phA[3])),
                      hmax2(hmax2(phA[4], phA[5]), hmax2(phA[6], phA[7])));
    half2v mB = hmax2(hmax2(hmax2(phB[0], phB[1]), hmax2(phB[2], phB[3])),
                      hmax2(hmax2(phB[4], phB[5]), hmax2(phB[6], phB[7])));
    half2v mx2 = hmax2(mA, mB);
    int mi = __builtin_bit_cast(int, mx2);
    mx2 = hmax2(mx2, __builtin_bit_cast(half2v, __shfl_xor(mi, 16)));
    mi = __builtin_bit_cast(int, mx2);
    mx2 = hmax2(mx2, __builtin_bit_cast(half2v, __shfl_xor(mi, 32)));
    const float mxf = fmaxf((float)mx2[0], (float)mx2[1]);
    const bool up = mxf > mrow + 4.0f;
    const float mn = up ? mxf : mrow;
    const float alpha = up ? exp2f(mrow - mn) : 1.0f;
    mrow = mn;

    const _Float16 mnh = (_Float16)mn;
    half2v mn2; mn2[0] = mnh; mn2[1] = mnh;
    half2v peA[8], peB[8];
#pragma unroll
    for (int i = 0; i < 8; ++i) {
      peA[i] = __builtin_elementwise_exp2(phA[i] - mn2);
      peB[i] = __builtin_elementwise_exp2(phB[i] - mn2);
    }

    if (__ballot(up)) {
      float alr[4];
#pragma unroll
      for (int r = 0; r < 4; ++r) alr[r] = __shfl(alpha, quad * 4 + r);
#pragma unroll
      for (int jb = 0; jb < 4; ++jb)
#pragma unroll
        for (int r = 0; r < 4; ++r) o16[jb][r] *= alr[r];
#pragma unroll
      for (int r = 0; r < 4; ++r) lacc[r] *= alr[r];
    }

    half8 pA[2], pB[2];
#pragma unroll
    for (int t = 0; t < 2; ++t) {
      half4v loA = __builtin_shufflevector(peA[4 * t],     peA[4 * t + 1], 0, 1, 2, 3);
      half4v hiA = __builtin_shufflevector(peA[4 * t + 2], peA[4 * t + 3], 0, 1, 2, 3);
      pA[t] = __builtin_shufflevector(loA, hiA, 0, 1, 2, 3, 4, 5, 6, 7);
      half4v loB = __builtin_shufflevector(peB[4 * t],     peB[4 * t + 1], 0, 1, 2, 3);
      half4v hiB = __builtin_shufflevector(peB[4 * t + 2], peB[4 * t + 3], 0, 1, 2, 3);
      pB[t] = __builtin_shufflevector(loB, hiB, 0, 1, 2, 3, 4, 5, 6, 7);
    }

    __builtin_amdgcn_s_setprio(1);
    lacc = MFMA32(pA[0], ones8, lacc);
    lacc = MFMA32(pA[1], ones8, lacc);
    lacc = MFMA32(pB[0], ones8, lacc);
    lacc = MFMA32(pB[1], ones8, lacc);

#pragma unroll
    for (int jb = 0; jb < 4; ++jb) {
      const int vrow = (jb * 16 + l16) * 64;
#pragma unroll
      for (int t = 0; t < 2; ++t) {
        half8 vA = *(const half8*)&V0[vrow + (((2 * quad + t) ^ rx) * 8)];
        half8 vB = *(const half8*)&V1[vrow + (((2 * quad + t) ^ rx) * 8)];
        o16[jb] = MFMA32(pA[t], vA, o16[jb]);
        o16[jb] = MFMA32(pB[t], vB, o16[jb]);
      }
    }
    __builtin_amdgcn_s_setprio(0);
  };

  int cur = 0;
  for (int p = 0; p < 16; ++p) {     // 16 pairs of 64-row K/V tiles
    if (p + 1 < 16) stage(p + 1, cur ^ 1);   // DMA; flies under compute
    compute_pair(Kbuf[cur][0], Kbuf[cur][1], Vbuf[cur][0], Vbuf[cur][1]);
    __syncthreads();                         // drains vmcnt: next pair ready
    cur ^= 1;
  }

  float linv[4];
#pragma unroll
  for (int r = 0; r < 4; ++r) linv[r] = 1.0f / lacc[r];   // no shuffles needed
#pragma unroll
  for (int jb = 0; jb < 4; ++jb) {
#pragma unroll
    for (int r = 0; r < 4; ++r) {
      const int row = q0 + wave * 16 + quad * 4 + r;
      attnb[(size_t)(b * S + row) * INNER + h * HD + jb * 16 + l16] =
          (_Float16)(o16[jb][r] * linv[r]);
    }
  }
}

// ---------------------------------------------------------------------------
extern "C" void kernel_launch(void* const* d_in, const int* in_sizes, int n_in,
                              void* d_out, int out_size, void* d_ws, size_t ws_size,
                              hipStream_t stream) {
  const float* hs    = (const float*)d_in[0];
  const float* rot   = (const float*)d_in[1];
  const float* w_qkv = (const float*)d_in[2];
  const float* b_qkv = (const float*)d_in[3];
  const float* nqw   = (const float*)d_in[4];
  const float* nkw   = (const float*)d_in[5];
  const float* w_out = (const float*)d_in[6];
  const float* b_out = (const float*)d_in[7];
  const float* hks   = (const float*)d_in[8];
  const int*   octx  = (const int*)d_in[9];

  _Float16* hsb   = (_Float16*)d_ws;                 // 0-8 MiB (attnb aliases)
  _Float16* attnb = hsb;
  _Float16* wqkvT = hsb   + (size_t)NTOK * DIM;      // 8-14 MiB
  _Float16* woutT = wqkvT + (size_t)QKVN * DIM;      // 14-16 MiB
  _Float16* qkvh  = woutT + (size_t)DIM * INNER;     // 16-40 MiB
  _Float16* q_h   = qkvh  + (size_t)NTOK * QKVN;     // 40-48 MiB
  _Float16* k_h   = q_h   + (size_t)B * NH * S * HD; // 48-56 MiB
  _Float16* vT    = k_h   + (size_t)B * NH * S * HD; // 56-64 MiB

  prep_all<<<3072, 256, 0, stream>>>(hs, w_qkv, w_out, hsb, wqkvT, woutT);

  gemm_bt<128, true, true, _Float16><<<dim3(QKVN / 128, NTOK / 128), 256, 0, stream>>>(
      hsb, wqkvT, b_qkv, qkvh, QKVN, DIM, vT);

  post_all<<<4096, 256, 0, stream>>>(qkvh, rot, nqw, nkw, hks, octx, q_h, k_h);

  attn_mfma<<<dim3(B * NH, S / 128), 512, 0, stream>>>(q_h, k_h, vT, attnb);

  gemm_bt<128, false, false, float><<<dim3(DIM / 128, NTOK / 128), 256, 0, stream>>>(
      attnb, woutT, b_out, (float*)d_out, DIM, INNER, nullptr);
}

// Round 13
// 205.782 us; speedup vs baseline: 1.0011x; 1.0011x over previous
//
#include <hip/hip_runtime.h>
#include <math.h>

typedef float    floatx4 __attribute__((ext_vector_type(4)));
typedef _Float16 half8   __attribute__((ext_vector_type(8)));
typedef _Float16 half4v  __attribute__((ext_vector_type(4)));
typedef _Float16 half2v  __attribute__((ext_vector_type(2)));
typedef __fp16   fp16x2  __attribute__((ext_vector_type(2)));

constexpr int B    = 2;
constexpr int S    = 2048;
constexpr int NH   = 16;
constexpr int HD   = 64;
constexpr int DIM  = 1024;
constexpr int INNER = 1024;
constexpr int QKVN = 3072;
constexpr int NTOK = 4096;
constexpr float EPS = 1e-5f;
constexpr float MAX_SCALE = 10.0f;
constexpr float SCALE_LOG2E = 0.125f * 1.4426950408889634f;

#define MFMA32(a, b, c) __builtin_amdgcn_mfma_f32_16x16x32_f16((a), (b), (c), 0, 0, 0)

__device__ __forceinline__ half2v pkrtz(float a, float b) {
  fp16x2 t = __builtin_amdgcn_cvt_pkrtz(a, b);
  return __builtin_bit_cast(half2v, t);
}
__device__ __forceinline__ half2v hmax2(half2v a, half2v b) {
  return __builtin_elementwise_max(a, b);
}
// RTE fp32x8 -> fp16x8 (matches the rounding of the deleted prep hs-pass).
__device__ __forceinline__ half8 cvt8(float4 a, float4 b) {
  half8 h;
  h[0] = (_Float16)a.x; h[1] = (_Float16)a.y; h[2] = (_Float16)a.z; h[3] = (_Float16)a.w;
  h[4] = (_Float16)b.x; h[5] = (_Float16)b.y; h[6] = (_Float16)b.z; h[7] = (_Float16)b.w;
  return h;
}

// Direct global->LDS DMA, 16 B per lane (attn staging only; all GEMM
// DMA-staging variants measured WORSE than reg-prefetch: R1 157, R2/3 158,
// R4 162, R6 159 vs R0 152 us non-attn. XCD remaps also regressed (R11).
// Run-to-run noise on this harness: +-2-3 us (R10 vs R12, identical code).)
__device__ __forceinline__ void gl_lds16(const _Float16* g, _Float16* l) {
  __builtin_amdgcn_global_load_lds(
      (__attribute__((address_space(1))) void*)g,
      (__attribute__((address_space(3))) void*)l, 16, 0, 0);
}

// ---------------------------------------------------------------------------
// Prep (R13: hs fp32->fp16 pass DELETED — gemm1 reads fp32 hs directly):
// blockIdx [0,768) transpose w_qkv; [768,1024) transpose w_out.
// ---------------------------------------------------------------------------
__device__ __forceinline__ void transpose_tile(const float* __restrict__ w,
                                               _Float16* __restrict__ wT,
                                               int K, int N, int k0, int n0,
                                               _Float16* T, int tid) {
#pragma unroll
  for (int i = 0; i < 4; ++i) {
    int id = tid + 256 * i;
    int r = id >> 4, c = id & 15;
    float4 v = *(const float4*)&w[(size_t)(k0 + r) * N + n0 + c * 4];
    half4v s; s[0] = (_Float16)v.x; s[1] = (_Float16)v.y;
    s[2] = (_Float16)v.z; s[3] = (_Float16)v.w;
    *(half4v*)&T[r * 72 + c * 4] = s;
  }
  __syncthreads();
#pragma unroll
  for (int i = 0; i < 2; ++i) {
    int id = tid + 256 * i;
    int n = id >> 3, cs = id & 7;
    half8 o;
#pragma unroll
    for (int jj = 0; jj < 8; ++jj) o[jj] = T[(cs * 8 + jj) * 72 + n];
    *(half8*)&wT[(size_t)(n0 + n) * K + k0 + cs * 8] = o;
  }
}

__global__ __launch_bounds__(256)
void prep_all(const float* __restrict__ w_qkv, const float* __restrict__ w_out,
              _Float16* __restrict__ wqkvT, _Float16* __restrict__ woutT) {
  __shared__ _Float16 T[64 * 72];
  const int bx = blockIdx.x, tid = threadIdx.x;
  if (bx < 768) {
    transpose_tile(w_qkv, wqkvT, DIM, QKVN, (bx / 48) * 64, (bx % 48) * 64, T, tid);
  } else {
    int id = bx - 768;
    transpose_tile(w_out, woutT, INNER, DIM, (id / 16) * 64, (id % 16) * 64, T, tid);
  }
}

// ---------------------------------------------------------------------------
// fp16 MFMA GEMM, reg-prefetch staging (measured-best mechanism), BK=64,
// default block mapping.
// A_F32 (R13): A is read as fp32 and converted (RTE) during staging — this
// deletes prep's 2048-block hs-convert pass entirely. +32 cvt/thread/K-step
// (~5% of MFMA issue cycles); A-panels (1 MB fp32) stay L2-resident.
// FUSE_V (R10): V-third blocks (n0 >= 2048) write accumulators DIRECTLY to
// vT in the attn fragment layout:
//   lane holds acc[i][j][r] = V[token quad*4 + i*16 + r][d = j*16+l16]
//   -> vT tile position d*64 + quad*16 + i*4 + r (contiguous per lane,j)
// ---------------------------------------------------------------------------
template<int BN, bool OUT_F16, bool FUSE_V, bool A_F32, typename OutT>
__global__ __launch_bounds__(256)
void gemm_bt(const void* __restrict__ Av, const _Float16* __restrict__ BT,
             const float* __restrict__ bias, OutT* __restrict__ C, int N, int K,
             _Float16* __restrict__ vt) {
  constexpr int NJ  = BN / 32;            // col-frags per wave
  constexpr int NSB = BN / 32;            // B staging slots per thread
  __shared__ _Float16 As[128 * 72];
  __shared__ _Float16 Bs[BN * 72];
  const int tid = threadIdx.x;
  const int wave = tid >> 6, lane = tid & 63, quad = lane >> 4, l16 = lane & 15;
  const int wm = wave >> 1, wn = wave & 1;
  const int m0 = blockIdx.y * 128, n0 = blockIdx.x * BN;

  // staging: thread covers rows r0+32s, k-cols [c0, c0+8) of the 64-wide slice
  const int r0 = tid >> 3;                // 0..31
  const int c0 = (tid & 7) * 8;           // 0..56
  const _Float16* Ap16 = (const _Float16*)Av + (size_t)(m0 + r0) * K + c0;
  const float*    Ap32 = (const float*)Av    + (size_t)(m0 + r0) * K + c0;
  const _Float16* Bp   = BT + (size_t)(n0 + r0) * K + c0;

  half8  ar[4];
  float4 arf[4][2];
  half8  br[NSB];
  if constexpr (A_F32) {
#pragma unroll
    for (int s = 0; s < 4; ++s) {
      arf[s][0] = *(const float4*)(Ap32 + (size_t)(32 * s) * K);
      arf[s][1] = *(const float4*)(Ap32 + (size_t)(32 * s) * K + 4);
    }
  } else {
#pragma unroll
    for (int s = 0; s < 4; ++s) ar[s] = *(const half8*)(Ap16 + (size_t)(32 * s) * K);
  }
#pragma unroll
  for (int s = 0; s < NSB; ++s) br[s] = *(const half8*)(Bp + (size_t)(32 * s) * K);

  floatx4 acc[4][NJ] = {};

  for (int k0 = 0; k0 < K; k0 += 64) {
    __syncthreads();
    if constexpr (A_F32) {
#pragma unroll
      for (int s = 0; s < 4; ++s)
        *(half8*)&As[(r0 + 32 * s) * 72 + c0] = cvt8(arf[s][0], arf[s][1]);
    } else {
#pragma unroll
      for (int s = 0; s < 4; ++s) *(half8*)&As[(r0 + 32 * s) * 72 + c0] = ar[s];
    }
#pragma unroll
    for (int s = 0; s < NSB; ++s) *(half8*)&Bs[(r0 + 32 * s) * 72 + c0] = br[s];
    if (k0 + 64 < K) {
      if constexpr (A_F32) {
#pragma unroll
        for (int s = 0; s < 4; ++s) {
          arf[s][0] = *(const float4*)(Ap32 + (size_t)(32 * s) * K + k0 + 64);
          arf[s][1] = *(const float4*)(Ap32 + (size_t)(32 * s) * K + k0 + 68);
        }
      } else {
#pragma unroll
        for (int s = 0; s < 4; ++s)
          ar[s] = *(const half8*)(Ap16 + (size_t)(32 * s) * K + k0 + 64);
      }
#pragma unroll
      for (int s = 0; s < NSB; ++s)
        br[s] = *(const half8*)(Bp + (size_t)(32 * s) * K + k0 + 64);
    }
    __syncthreads();
#pragma unroll
    for (int ks = 0; ks < 2; ++ks) {
      half8 a[4], b[NJ];
#pragma unroll
      for (int i = 0; i < 4; ++i)
        a[i] = *(const half8*)&As[(wm * 64 + i * 16 + l16) * 72 + ks * 32 + quad * 8];
#pragma unroll
      for (int j = 0; j < NJ; ++j)
        b[j] = *(const half8*)&Bs[(wn * (BN / 2) + j * 16 + l16) * 72 + ks * 32 + quad * 8];
#pragma unroll
      for (int i = 0; i < 4; ++i)
#pragma unroll
        for (int j = 0; j < NJ; ++j)
          acc[i][j] = MFMA32(a[i], b[j], acc[i][j]);
    }
  }

  const int rb = m0 + wm * 64 + quad * 4;
  const int cb = n0 + wn * (BN / 2) + l16;

  if constexpr (FUSE_V) {
    if (n0 >= 2 * INNER) {
      // V block: write vT directly (attn fragment layout), skip qkvh.
      const int h  = ((n0 - 2 * INNER) >> 6) + wn;     // head (one per wave)
      const int bb = m0 >> 11;                          // batch
      const int kt = ((m0 & (S - 1)) >> 6) + wm;        // 64-token tile idx
      _Float16* orow = vt + ((size_t)(bb * NH + h) * 32 + kt) * (64 * 64);
#pragma unroll
      for (int j = 0; j < NJ; ++j) {
        const float bj = bias[cb + j * 16];
        const int d = j * 16 + l16;
#pragma unroll
        for (int i = 0; i < 4; ++i) {
          half4v o;
#pragma unroll
          for (int r = 0; r < 4; ++r) o[r] = (_Float16)(acc[i][j][r] + bj);
          *(half4v*)&orow[d * 64 + quad * 16 + i * 4] = o;
        }
      }
      return;
    }
  }

#pragma unroll
  for (int j = 0; j < NJ; ++j) {
    const float bj = bias[cb + j * 16];
#pragma unroll
    for (int i = 0; i < 4; ++i) {
#pragma unroll
      for (int r = 0; r < 4; ++r) {
        float v = acc[i][j][r] + bj;
        size_t idx2 = (size_t)(rb + i * 16 + r) * N + cb + j * 16;
        if constexpr (OUT_F16) C[idx2] = (_Float16)v; else C[idx2] = v;
      }
    }
  }
}

// ---------------------------------------------------------------------------
// Fused post (V-transpose lives in gemm1's epilogue since R10):
// 4096 blocks, per-token RMSNorm + rotary + hist-scale on q,k only.
// ---------------------------------------------------------------------------
__global__ __launch_bounds__(256)
void post_all(const _Float16* __restrict__ qkvh, const float* __restrict__ rot,
              const float* __restrict__ nqw, const float* __restrict__ nkw,
              const float* __restrict__ hks, const int* __restrict__ octx,
              _Float16* __restrict__ qo_, _Float16* __restrict__ ko_) {
  __shared__ float red[8];
  const int tid = threadIdx.x;
  const int token = blockIdx.x;
  const int b = token >> 11, spos = token & (S - 1);
  const _Float16* qrow = qkvh + (size_t)token * QKVN;
  const _Float16* krow = qrow + INNER;
  const float* r = rot + (size_t)token * (2 * HD);

  const int e0 = tid * 4;
  half4v qs = *(const half4v*)(qrow + e0);
  half4v ks = *(const half4v*)(krow + e0);
  float q4[4], k4[4];
#pragma unroll
  for (int i = 0; i < 4; ++i) { q4[i] = (float)qs[i]; k4[i] = (float)ks[i]; }

  float sq = 0.f, sk = 0.f;
#pragma unroll
  for (int i = 0; i < 4; ++i) { sq += q4[i] * q4[i]; sk += k4[i] * k4[i]; }
#pragma unroll
  for (int msk = 1; msk < 64; msk <<= 1) {
    sq += __shfl_xor(sq, msk);
    sk += __shfl_xor(sk, msk);
  }
  const int wv = tid >> 6;
  if ((tid & 63) == 0) { red[wv] = sq; red[4 + wv] = sk; }
  __syncthreads();
  sq = red[0] + red[1] + red[2] + red[3];
  sk = red[4] + red[5] + red[6] + red[7];

  const float qinv = 1.0f / sqrtf(sq * (1.0f / INNER) + EPS);
  const float kinv = 1.0f / sqrtf(sk * (1.0f / INNER) + EPS);

#pragma unroll
  for (int i = 0; i < 4; ++i) {
    q4[i] = q4[i] * qinv * nqw[e0 + i];
    k4[i] = k4[i] * kinv * nkw[e0 + i];
  }

  const int h = e0 >> 6, d0 = e0 & (HD - 1);
  const float c0 = r[d0],     s0 = r[HD + d0 + 1];
  const float c1 = r[d0 + 2], s1 = r[HD + d0 + 3];

  float qo[4], ko[4];
  qo[0] = q4[0] * c0 - q4[1] * s0;
  qo[1] = q4[0] * s0 + q4[1] * c0;
  qo[2] = q4[2] * c1 - q4[3] * s1;
  qo[3] = q4[2] * s1 + q4[3] * c1;
  ko[0] = k4[0] * c0 - k4[1] * s0;
  ko[1] = k4[0] * s0 + k4[1] * c0;
  ko[2] = k4[2] * c1 - k4[3] * s1;
  ko[3] = k4[2] * s1 + k4[3] * c1;

  const int hist = S - octx[0];
  if (hist > 0 && spos < hist) {
    const float sig = 1.0f / (1.0f + expf(-hks[h]));
    const float sc = 1.0f + sig * (MAX_SCALE - 1.0f);
#pragma unroll
    for (int i = 0; i < 4; ++i) ko[i] *= sc;
  }

  half4v qo4, ko4;
#pragma unroll
  for (int i = 0; i < 4; ++i) {
    qo4[i] = (_Float16)(qo[i] * SCALE_LOG2E);
    ko4[i] = (_Float16)ko[i];
  }
  const size_t obase = ((size_t)(b * NH + h) * S + spos) * HD + d0;
  *(half4v*)(qo_ + obase) = qo4;
  *(half4v*)(ko_ + obase) = ko4;
}

// ---------------------------------------------------------------------------
// MFMA flash attention — R7 version verbatim (measured best: ~51.6 us).
// 512 thr = 8 waves, 16 Q-rows/wave, 2 K-tiles per barrier with shared
// max-update, DMA staging with XOR source swizzle, defer-max, ones-MFMA
// row-sum, PV via 16x16x32, T5 setprio around MFMA clusters.
// ---------------------------------------------------------------------------
__global__ __launch_bounds__(512, 4)
void attn_mfma(const _Float16* __restrict__ qb, const _Float16* __restrict__ kb,
               const _Float16* __restrict__ vt, _Float16* __restrict__ attnb) {
  __shared__ _Float16 Kbuf[2][2][64 * 64];
  __shared__ _Float16 Vbuf[2][2][64 * 64];
  const int bh = blockIdx.x;
  const int b = bh >> 4, h = bh & 15;
  const int q0 = blockIdx.y * 128;
  const int tid = threadIdx.x;
  const int wave = tid >> 6, lane = tid & 63, quad = lane >> 4, l16 = lane & 15;
  const int rx = l16 & 7;

  const _Float16* qbh = qb + (size_t)bh * S * HD;
  const _Float16* kbh = kb + (size_t)bh * S * HD;
  const _Float16* vbh = vt + (size_t)bh * S * HD;

  half8 aq[2];
#pragma unroll
  for (int ks = 0; ks < 2; ++ks)
    aq[ks] = *(const half8*)&qbh[(size_t)(q0 + wave * 16 + l16) * HD + ks * 32 + quad * 8];

  const int srow = wave * 8 + (lane >> 3);
  const int soff = srow * 64 + (((lane & 7) ^ (srow & 7)) * 8);

  auto stage = [&](int p, int buf) {
    const _Float16* kt = kbh + (size_t)p * 8192;
    const _Float16* vp = vbh + (size_t)p * 8192;
    gl_lds16(kt + soff,        &Kbuf[buf][0][wave * 512]);
    gl_lds16(kt + 4096 + soff, &Kbuf[buf][1][wave * 512]);
    gl_lds16(vp + soff,        &Vbuf[buf][0][wave * 512]);
    gl_lds16(vp + 4096 + soff, &Vbuf[buf][1][wave * 512]);
  };

  stage(0, 0);
  __syncthreads();   // drains vmcnt(0): pair 0 resident

  floatx4 o16[4] = {};
  floatx4 lacc = {};                      // row-sums, same layout as o16 rows
  float mrow = -INFINITY;

  half8 ones8;
#pragma unroll
  for (int i = 0; i < 8; ++i) ones8[i] = (_Float16)1.f;

  auto compute_pair = [&](const _Float16* K0, const _Float16* K1,
                          const _Float16* V0, const _Float16* V1) {
    floatx4 scA[4] = {}, scB[4] = {};
    __builtin_amdgcn_s_setprio(1);
#pragma unroll
    for (int jj = 0; jj < 4; ++jj) {
#pragma unroll
      for (int ks = 0; ks < 2; ++ks) {
        const int co = (jj * 16 + l16) * 64 + (((ks * 4 + quad) ^ rx) * 8);
        half8 akA = *(const half8*)&K0[co];
        half8 akB = *(const half8*)&K1[co];
        scA[jj] = MFMA32(akA, aq[ks], scA[jj]);
        scB[jj] = MFMA32(akB, aq[ks], scB[jj]);
      }
    }
    __builtin_amdgcn_s_setprio(0);

    half2v phA[8], phB[8];
#pragma unroll
    for (int jj = 0; jj < 4; ++jj) {
      phA[jj * 2]     = pkrtz(scA[jj][0], scA[jj][1]);
      phA[jj * 2 + 1] = pkrtz(scA[jj][2], scA[jj][3]);
      phB[jj * 2]     = pkrtz(scB[jj][0], scB[jj][1]);
      phB[jj * 2 + 1] = pkrtz(scB[jj][2], scB[jj][3]);
    }
    half2v mA = hmax2(hmax2(hmax2(phA[0], phA[1]), hmax2(phA[2], phA[3])),
                      hmax2(hmax2(phA[4], phA[5]), hmax2(phA[6], phA[7])));
    half2v mB = hmax2(hmax2(hmax2(phB[0], phB[1]), hmax2(phB[2], phB[3])),
                      hmax2(hmax2(phB[4], phB[5]), hmax2(phB[6], phB[7])));
    half2v mx2 = hmax2(mA, mB);
    int mi = __builtin_bit_cast(int, mx2);
    mx2 = hmax2(mx2, __builtin_bit_cast(half2v, __shfl_xor(mi, 16)));
    mi = __builtin_bit_cast(int, mx2);
    mx2 = hmax2(mx2, __builtin_bit_cast(half2v, __shfl_xor(mi, 32)));
    const float mxf = fmaxf((float)mx2[0], (float)mx2[1]);
    const bool up = mxf > mrow + 4.0f;
    const float mn = up ? mxf : mrow;
    const float alpha = up ? exp2f(mrow - mn) : 1.0f;
    mrow = mn;

    const _Float16 mnh = (_Float16)mn;
    half2v mn2; mn2[0] = mnh; mn2[1] = mnh;
    half2v peA[8], peB[8];
#pragma unroll
    for (int i = 0; i < 8; ++i) {
      peA[i] = __builtin_elementwise_exp2(phA[i] - mn2);
      peB[i] = __builtin_elementwise_exp2(phB[i] - mn2);
    }

    if (__ballot(up)) {
      float alr[4];
#pragma unroll
      for (int r = 0; r < 4; ++r) alr[r] = __shfl(alpha, quad * 4 + r);
#pragma unroll
      for (int jb = 0; jb < 4; ++jb)
#pragma unroll
        for (int r = 0; r < 4; ++r) o16[jb][r] *= alr[r];
#pragma unroll
      for (int r = 0; r < 4; ++r) lacc[r] *= alr[r];
    }

    half8 pA[2], pB[2];
#pragma unroll
    for (int t = 0; t < 2; ++t) {
      half4v loA = __builtin_shufflevector(peA[4 * t],     peA[4 * t + 1], 0, 1, 2, 3);
      half4v hiA = __builtin_shufflevector(peA[4 * t + 2], peA[4 * t + 3], 0, 1, 2, 3);
      pA[t] = __builtin_shufflevector(loA, hiA, 0, 1, 2, 3, 4, 5, 6, 7);
      half4v loB = __builtin_shufflevector(peB[4 * t],     peB[4 * t + 1], 0, 1, 2, 3);
      half4v hiB = __builtin_shufflevector(peB[4 * t + 2], peB[4 * t + 3], 0, 1, 2, 3);
      pB[t] = __builtin_shufflevector(loB, hiB, 0, 1, 2, 3, 4, 5, 6, 7);
    }

    __builtin_amdgcn_s_setprio(1);
    lacc = MFMA32(pA[0], ones8, lacc);
    lacc = MFMA32(pA[1], ones8, lacc);
    lacc = MFMA32(pB[0], ones8, lacc);
    lacc = MFMA32(pB[1], ones8, lacc);

#pragma unroll
    for (int jb = 0; jb < 4; ++jb) {
      const int vrow = (jb * 16 + l16) * 64;
#pragma unroll
      for (int t = 0; t < 2; ++t) {
        half8 vA = *(const half8*)&V0[vrow + (((2 * quad + t) ^ rx) * 8)];
        half8 vB = *(const half8*)&V1[vrow + (((2 * quad + t) ^ rx) * 8)];
        o16[jb] = MFMA32(pA[t], vA, o16[jb]);
        o16[jb] = MFMA32(pB[t], vB, o16[jb]);
      }
    }
    __builtin_amdgcn_s_setprio(0);
  };

  int cur = 0;
  for (int p = 0; p < 16; ++p) {     // 16 pairs of 64-row K/V tiles
    if (p + 1 < 16) stage(p + 1, cur ^ 1);   // DMA; flies under compute
    compute_pair(Kbuf[cur][0], Kbuf[cur][1], Vbuf[cur][0], Vbuf[cur][1]);
    __syncthreads();                         // drains vmcnt: next pair ready
    cur ^= 1;
  }

  float linv[4];
#pragma unroll
  for (int r = 0; r < 4; ++r) linv[r] = 1.0f / lacc[r];   // no shuffles needed
#pragma unroll
  for (int jb = 0; jb < 4; ++jb) {
#pragma unroll
    for (int r = 0; r < 4; ++r) {
      const int row = q0 + wave * 16 + quad * 4 + r;
      attnb[(size_t)(b * S + row) * INNER + h * HD + jb * 16 + l16] =
          (_Float16)(o16[jb][r] * linv[r]);
    }
  }
}

// ---------------------------------------------------------------------------
extern "C" void kernel_launch(void* const* d_in, const int* in_sizes, int n_in,
                              void* d_out, int out_size, void* d_ws, size_t ws_size,
                              hipStream_t stream) {
  const float* hs    = (const float*)d_in[0];
  const float* rot   = (const float*)d_in[1];
  const float* w_qkv = (const float*)d_in[2];
  const float* b_qkv = (const float*)d_in[3];
  const float* nqw   = (const float*)d_in[4];
  const float* nkw   = (const float*)d_in[5];
  const float* w_out = (const float*)d_in[6];
  const float* b_out = (const float*)d_in[7];
  const float* hks   = (const float*)d_in[8];
  const int*   octx  = (const int*)d_in[9];

  _Float16* attnb = (_Float16*)d_ws;                 // 0-8 MiB
  _Float16* wqkvT = attnb + (size_t)NTOK * DIM;      // 8-14 MiB
  _Float16* woutT = wqkvT + (size_t)QKVN * DIM;      // 14-16 MiB
  _Float16* qkvh  = woutT + (size_t)DIM * INNER;     // 16-40 MiB
  _Float16* q_h   = qkvh  + (size_t)NTOK * QKVN;     // 40-48 MiB
  _Float16* k_h   = q_h   + (size_t)B * NH * S * HD; // 48-56 MiB
  _Float16* vT    = k_h   + (size_t)B * NH * S * HD; // 56-64 MiB

  prep_all<<<1024, 256, 0, stream>>>(w_qkv, w_out, wqkvT, woutT);

  gemm_bt<128, true, true, true, _Float16><<<dim3(QKVN / 128, NTOK / 128), 256, 0, stream>>>(
      hs, wqkvT, b_qkv, qkvh, QKVN, DIM, vT);

  post_all<<<4096, 256, 0, stream>>>(qkvh, rot, nqw, nkw, hks, octx, q_h, k_h);

  attn_mfma<<<dim3(B * NH, S / 128), 512, 0, stream>>>(q_h, k_h, vT, attnb);

  gemm_bt<128, false, false, false, float><<<dim3(DIM / 128, NTOK / 128), 256, 0, stream>>>(
      attnb, woutT, b_out, (float*)d_out, DIM, INNER, nullptr);
}

// Round 14
// 203.466 us; speedup vs baseline: 1.0125x; 1.0114x over previous
//
#include <hip/hip_runtime.h>
#include <math.h>

typedef float    floatx4 __attribute__((ext_vector_type(4)));
typedef _Float16 half8   __attribute__((ext_vector_type(8)));
typedef _Float16 half4v  __attribute__((ext_vector_type(4)));
typedef _Float16 half2v  __attribute__((ext_vector_type(2)));
typedef __fp16   fp16x2  __attribute__((ext_vector_type(2)));

constexpr int B    = 2;
constexpr int S    = 2048;
constexpr int NH   = 16;
constexpr int HD   = 64;
constexpr int DIM  = 1024;
constexpr int INNER = 1024;
constexpr int QKVN = 3072;
constexpr int NTOK = 4096;
constexpr float EPS = 1e-5f;
constexpr float MAX_SCALE = 10.0f;
constexpr float SCALE_LOG2E = 0.125f * 1.4426950408889634f;

#define MFMA32(a, b, c) __builtin_amdgcn_mfma_f32_16x16x32_f16((a), (b), (c), 0, 0, 0)

__device__ __forceinline__ half2v pkrtz(float a, float b) {
  fp16x2 t = __builtin_amdgcn_cvt_pkrtz(a, b);
  return __builtin_bit_cast(half2v, t);
}
__device__ __forceinline__ half2v hmax2(half2v a, half2v b) {
  return __builtin_elementwise_max(a, b);
}
// RTE fp32x8 -> fp16x8 (matches the rounding of the deleted prep hs-pass).
__device__ __forceinline__ half8 cvt8(float4 a, float4 b) {
  half8 h;
  h[0] = (_Float16)a.x; h[1] = (_Float16)a.y; h[2] = (_Float16)a.z; h[3] = (_Float16)a.w;
  h[4] = (_Float16)b.x; h[5] = (_Float16)b.y; h[6] = (_Float16)b.z; h[7] = (_Float16)b.w;
  return h;
}

// Direct global->LDS DMA, 16 B per lane (attn staging only; all GEMM
// DMA-staging variants measured WORSE than reg-prefetch. Noise: +-2-3 us.)
__device__ __forceinline__ void gl_lds16(const _Float16* g, _Float16* l) {
  __builtin_amdgcn_global_load_lds(
      (__attribute__((address_space(1))) void*)g,
      (__attribute__((address_space(3))) void*)l, 16, 0, 0);
}

// ---------------------------------------------------------------------------
// Prep: blockIdx [0,768) transpose w_qkv; [768,1024) transpose w_out.
// (hs fp32->fp16 pass deleted since R13 — gemm1 reads fp32 hs directly.)
// ---------------------------------------------------------------------------
__device__ __forceinline__ void transpose_tile(const float* __restrict__ w,
                                               _Float16* __restrict__ wT,
                                               int K, int N, int k0, int n0,
                                               _Float16* T, int tid) {
#pragma unroll
  for (int i = 0; i < 4; ++i) {
    int id = tid + 256 * i;
    int r = id >> 4, c = id & 15;
    float4 v = *(const float4*)&w[(size_t)(k0 + r) * N + n0 + c * 4];
    half4v s; s[0] = (_Float16)v.x; s[1] = (_Float16)v.y;
    s[2] = (_Float16)v.z; s[3] = (_Float16)v.w;
    *(half4v*)&T[r * 72 + c * 4] = s;
  }
  __syncthreads();
#pragma unroll
  for (int i = 0; i < 2; ++i) {
    int id = tid + 256 * i;
    int n = id >> 3, cs = id & 7;
    half8 o;
#pragma unroll
    for (int jj = 0; jj < 8; ++jj) o[jj] = T[(cs * 8 + jj) * 72 + n];
    *(half8*)&wT[(size_t)(n0 + n) * K + k0 + cs * 8] = o;
  }
}

__global__ __launch_bounds__(256)
void prep_all(const float* __restrict__ w_qkv, const float* __restrict__ w_out,
              _Float16* __restrict__ wqkvT, _Float16* __restrict__ woutT) {
  __shared__ _Float16 T[64 * 72];
  const int bx = blockIdx.x, tid = threadIdx.x;
  if (bx < 768) {
    transpose_tile(w_qkv, wqkvT, DIM, QKVN, (bx / 48) * 64, (bx % 48) * 64, T, tid);
  } else {
    int id = bx - 768;
    transpose_tile(w_out, woutT, INNER, DIM, (id / 16) * 64, (id % 16) * 64, T, tid);
  }
}

// ---------------------------------------------------------------------------
// fp16 MFMA GEMM, reg-prefetch staging, BK=64.
// R14: GRID AXES SWAPPED (x = m-tile, y = n-tile). R13's counters showed
// gemm1 fetch-bound: FETCH 74 MB vs 22 ideal. With x=n, the 24 blocks
// sharing an A-panel had consecutive linear ids -> spread over all 8 XCDs
// -> each panel L2-filled 8x. With x=m (32 tiles, 32%8==0), blocks sharing
// panel m have lin = n*32+m -> ALL land on XCD m%8: each XCD keeps its 4
// A-panels (2 MB) L2-resident; A fetched ~once. B replicates x8 but per-XCD
// B footprint cycles through L2. Predicted FETCH 74 -> ~30-45 MB.
// A_F32 (R13): A read as fp32, converted RTE during staging (prep pass
// deleted). FUSE_V (R10): V-third blocks write vT directly in attn layout.
// ---------------------------------------------------------------------------
template<int BN, bool OUT_F16, bool FUSE_V, bool A_F32, typename OutT>
__global__ __launch_bounds__(256)
void gemm_bt(const void* __restrict__ Av, const _Float16* __restrict__ BT,
             const float* __restrict__ bias, OutT* __restrict__ C, int N, int K,
             _Float16* __restrict__ vt) {
  constexpr int NJ  = BN / 32;            // col-frags per wave
  constexpr int NSB = BN / 32;            // B staging slots per thread
  __shared__ _Float16 As[128 * 72];
  __shared__ _Float16 Bs[BN * 72];
  const int tid = threadIdx.x;
  const int wave = tid >> 6, lane = tid & 63, quad = lane >> 4, l16 = lane & 15;
  const int wm = wave >> 1, wn = wave & 1;
  const int m0 = blockIdx.x * 128, n0 = blockIdx.y * BN;   // R14: x=m, y=n

  // staging: thread covers rows r0+32s, k-cols [c0, c0+8) of the 64-wide slice
  const int r0 = tid >> 3;                // 0..31
  const int c0 = (tid & 7) * 8;           // 0..56
  const _Float16* Ap16 = (const _Float16*)Av + (size_t)(m0 + r0) * K + c0;
  const float*    Ap32 = (const float*)Av    + (size_t)(m0 + r0) * K + c0;
  const _Float16* Bp   = BT + (size_t)(n0 + r0) * K + c0;

  half8  ar[4];
  float4 arf[4][2];
  half8  br[NSB];
  if constexpr (A_F32) {
#pragma unroll
    for (int s = 0; s < 4; ++s) {
      arf[s][0] = *(const float4*)(Ap32 + (size_t)(32 * s) * K);
      arf[s][1] = *(const float4*)(Ap32 + (size_t)(32 * s) * K + 4);
    }
  } else {
#pragma unroll
    for (int s = 0; s < 4; ++s) ar[s] = *(const half8*)(Ap16 + (size_t)(32 * s) * K);
  }
#pragma unroll
  for (int s = 0; s < NSB; ++s) br[s] = *(const half8*)(Bp + (size_t)(32 * s) * K);

  floatx4 acc[4][NJ] = {};

  for (int k0 = 0; k0 < K; k0 += 64) {
    __syncthreads();
    if constexpr (A_F32) {
#pragma unroll
      for (int s = 0; s < 4; ++s)
        *(half8*)&As[(r0 + 32 * s) * 72 + c0] = cvt8(arf[s][0], arf[s][1]);
    } else {
#pragma unroll
      for (int s = 0; s < 4; ++s) *(half8*)&As[(r0 + 32 * s) * 72 + c0] = ar[s];
    }
#pragma unroll
    for (int s = 0; s < NSB; ++s) *(half8*)&Bs[(r0 + 32 * s) * 72 + c0] = br[s];
    if (k0 + 64 < K) {
      if constexpr (A_F32) {
#pragma unroll
        for (int s = 0; s < 4; ++s) {
          arf[s][0] = *(const float4*)(Ap32 + (size_t)(32 * s) * K + k0 + 64);
          arf[s][1] = *(const float4*)(Ap32 + (size_t)(32 * s) * K + k0 + 68);
        }
      } else {
#pragma unroll
        for (int s = 0; s < 4; ++s)
          ar[s] = *(const half8*)(Ap16 + (size_t)(32 * s) * K + k0 + 64);
      }
#pragma unroll
      for (int s = 0; s < NSB; ++s)
        br[s] = *(const half8*)(Bp + (size_t)(32 * s) * K + k0 + 64);
    }
    __syncthreads();
#pragma unroll
    for (int ks = 0; ks < 2; ++ks) {
      half8 a[4], b[NJ];
#pragma unroll
      for (int i = 0; i < 4; ++i)
        a[i] = *(const half8*)&As[(wm * 64 + i * 16 + l16) * 72 + ks * 32 + quad * 8];
#pragma unroll
      for (int j = 0; j < NJ; ++j)
        b[j] = *(const half8*)&Bs[(wn * (BN / 2) + j * 16 + l16) * 72 + ks * 32 + quad * 8];
#pragma unroll
      for (int i = 0; i < 4; ++i)
#pragma unroll
        for (int j = 0; j < NJ; ++j)
          acc[i][j] = MFMA32(a[i], b[j], acc[i][j]);
    }
  }

  const int rb = m0 + wm * 64 + quad * 4;
  const int cb = n0 + wn * (BN / 2) + l16;

  if constexpr (FUSE_V) {
    if (n0 >= 2 * INNER) {
      // V block: write vT directly (attn fragment layout), skip qkvh.
      const int h  = ((n0 - 2 * INNER) >> 6) + wn;     // head (one per wave)
      const int bb = m0 >> 11;                          // batch
      const int kt = ((m0 & (S - 1)) >> 6) + wm;        // 64-token tile idx
      _Float16* orow = vt + ((size_t)(bb * NH + h) * 32 + kt) * (64 * 64);
#pragma unroll
      for (int j = 0; j < NJ; ++j) {
        const float bj = bias[cb + j * 16];
        const int d = j * 16 + l16;
#pragma unroll
        for (int i = 0; i < 4; ++i) {
          half4v o;
#pragma unroll
          for (int r = 0; r < 4; ++r) o[r] = (_Float16)(acc[i][j][r] + bj);
          *(half4v*)&orow[d * 64 + quad * 16 + i * 4] = o;
        }
      }
      return;
    }
  }

#pragma unroll
  for (int j = 0; j < NJ; ++j) {
    const float bj = bias[cb + j * 16];
#pragma unroll
    for (int i = 0; i < 4; ++i) {
#pragma unroll
      for (int r = 0; r < 4; ++r) {
        float v = acc[i][j][r] + bj;
        size_t idx2 = (size_t)(rb + i * 16 + r) * N + cb + j * 16;
        if constexpr (OUT_F16) C[idx2] = (_Float16)v; else C[idx2] = v;
      }
    }
  }
}

// ---------------------------------------------------------------------------
// Fused post (V-transpose lives in gemm1's epilogue since R10):
// 4096 blocks, per-token RMSNorm + rotary + hist-scale on q,k only.
// ---------------------------------------------------------------------------
__global__ __launch_bounds__(256)
void post_all(const _Float16* __restrict__ qkvh, const float* __restrict__ rot,
              const float* __restrict__ nqw, const float* __restrict__ nkw,
              const float* __restrict__ hks, const int* __restrict__ octx,
              _Float16* __restrict__ qo_, _Float16* __restrict__ ko_) {
  __shared__ float red[8];
  const int tid = threadIdx.x;
  const int token = blockIdx.x;
  const int b = token >> 11, spos = token & (S - 1);
  const _Float16* qrow = qkvh + (size_t)token * QKVN;
  const _Float16* krow = qrow + INNER;
  const float* r = rot + (size_t)token * (2 * HD);

  const int e0 = tid * 4;
  half4v qs = *(const half4v*)(qrow + e0);
  half4v ks = *(const half4v*)(krow + e0);
  float q4[4], k4[4];
#pragma unroll
  for (int i = 0; i < 4; ++i) { q4[i] = (float)qs[i]; k4[i] = (float)ks[i]; }

  float sq = 0.f, sk = 0.f;
#pragma unroll
  for (int i = 0; i < 4; ++i) { sq += q4[i] * q4[i]; sk += k4[i] * k4[i]; }
#pragma unroll
  for (int msk = 1; msk < 64; msk <<= 1) {
    sq += __shfl_xor(sq, msk);
    sk += __shfl_xor(sk, msk);
  }
  const int wv = tid >> 6;
  if ((tid & 63) == 0) { red[wv] = sq; red[4 + wv] = sk; }
  __syncthreads();
  sq = red[0] + red[1] + red[2] + red[3];
  sk = red[4] + red[5] + red[6] + red[7];

  const float qinv = 1.0f / sqrtf(sq * (1.0f / INNER) + EPS);
  const float kinv = 1.0f / sqrtf(sk * (1.0f / INNER) + EPS);

#pragma unroll
  for (int i = 0; i < 4; ++i) {
    q4[i] = q4[i] * qinv * nqw[e0 + i];
    k4[i] = k4[i] * kinv * nkw[e0 + i];
  }

  const int h = e0 >> 6, d0 = e0 & (HD - 1);
  const float c0 = r[d0],     s0 = r[HD + d0 + 1];
  const float c1 = r[d0 + 2], s1 = r[HD + d0 + 3];

  float qo[4], ko[4];
  qo[0] = q4[0] * c0 - q4[1] * s0;
  qo[1] = q4[0] * s0 + q4[1] * c0;
  qo[2] = q4[2] * c1 - q4[3] * s1;
  qo[3] = q4[2] * s1 + q4[3] * c1;
  ko[0] = k4[0] * c0 - k4[1] * s0;
  ko[1] = k4[0] * s0 + k4[1] * c0;
  ko[2] = k4[2] * c1 - k4[3] * s1;
  ko[3] = k4[2] * s1 + k4[3] * c1;

  const int hist = S - octx[0];
  if (hist > 0 && spos < hist) {
    const float sig = 1.0f / (1.0f + expf(-hks[h]));
    const float sc = 1.0f + sig * (MAX_SCALE - 1.0f);
#pragma unroll
    for (int i = 0; i < 4; ++i) ko[i] *= sc;
  }

  half4v qo4, ko4;
#pragma unroll
  for (int i = 0; i < 4; ++i) {
    qo4[i] = (_Float16)(qo[i] * SCALE_LOG2E);
    ko4[i] = (_Float16)ko[i];
  }
  const size_t obase = ((size_t)(b * NH + h) * S + spos) * HD + d0;
  *(half4v*)(qo_ + obase) = qo4;
  *(half4v*)(ko_ + obase) = ko4;
}

// ---------------------------------------------------------------------------
// MFMA flash attention — R7 version verbatim (measured best: ~51.6 us).
// 512 thr = 8 waves, 16 Q-rows/wave, 2 K-tiles per barrier with shared
// max-update, DMA staging with XOR source swizzle, defer-max, ones-MFMA
// row-sum, PV via 16x16x32, T5 setprio around MFMA clusters.
// ---------------------------------------------------------------------------
__global__ __launch_bounds__(512, 4)
void attn_mfma(const _Float16* __restrict__ qb, const _Float16* __restrict__ kb,
               const _Float16* __restrict__ vt, _Float16* __restrict__ attnb) {
  __shared__ _Float16 Kbuf[2][2][64 * 64];
  __shared__ _Float16 Vbuf[2][2][64 * 64];
  const int bh = blockIdx.x;
  const int b = bh >> 4, h = bh & 15;
  const int q0 = blockIdx.y * 128;
  const int tid = threadIdx.x;
  const int wave = tid >> 6, lane = tid & 63, quad = lane >> 4, l16 = lane & 15;
  const int rx = l16 & 7;

  const _Float16* qbh = qb + (size_t)bh * S * HD;
  const _Float16* kbh = kb + (size_t)bh * S * HD;
  const _Float16* vbh = vt + (size_t)bh * S * HD;

  half8 aq[2];
#pragma unroll
  for (int ks = 0; ks < 2; ++ks)
    aq[ks] = *(const half8*)&qbh[(size_t)(q0 + wave * 16 + l16) * HD + ks * 32 + quad * 8];

  const int srow = wave * 8 + (lane >> 3);
  const int soff = srow * 64 + (((lane & 7) ^ (srow & 7)) * 8);

  auto stage = [&](int p, int buf) {
    const _Float16* kt = kbh + (size_t)p * 8192;
    const _Float16* vp = vbh + (size_t)p * 8192;
    gl_lds16(kt + soff,        &Kbuf[buf][0][wave * 512]);
    gl_lds16(kt + 4096 + soff, &Kbuf[buf][1][wave * 512]);
    gl_lds16(vp + soff,        &Vbuf[buf][0][wave * 512]);
    gl_lds16(vp + 4096 + soff, &Vbuf[buf][1][wave * 512]);
  };

  stage(0, 0);
  __syncthreads();   // drains vmcnt(0): pair 0 resident

  floatx4 o16[4] = {};
  floatx4 lacc = {};                      // row-sums, same layout as o16 rows
  float mrow = -INFINITY;

  half8 ones8;
#pragma unroll
  for (int i = 0; i < 8; ++i) ones8[i] = (_Float16)1.f;

  auto compute_pair = [&](const _Float16* K0, const _Float16* K1,
                          const _Float16* V0, const _Float16* V1) {
    floatx4 scA[4] = {}, scB[4] = {};
    __builtin_amdgcn_s_setprio(1);
#pragma unroll
    for (int jj = 0; jj < 4; ++jj) {
#pragma unroll
      for (int ks = 0; ks < 2; ++ks) {
        const int co = (jj * 16 + l16) * 64 + (((ks * 4 + quad) ^ rx) * 8);
        half8 akA = *(const half8*)&K0[co];
        half8 akB = *(const half8*)&K1[co];
        scA[jj] = MFMA32(akA, aq[ks], scA[jj]);
        scB[jj] = MFMA32(akB, aq[ks], scB[jj]);
      }
    }
    __builtin_amdgcn_s_setprio(0);

    half2v phA[8], phB[8];
#pragma unroll
    for (int jj = 0; jj < 4; ++jj) {
      phA[jj * 2]     = pkrtz(scA[jj][0], scA[jj][1]);
      phA[jj * 2 + 1] = pkrtz(scA[jj][2], scA[jj][3]);
      phB[jj * 2]     = pkrtz(scB[jj][0], scB[jj][1]);
      phB[jj * 2 + 1] = pkrtz(scB[jj][2], scB[jj][3]);
    }
    half2v mA = hmax2(hmax2(hmax2(phA[0], phA[1]), hmax2(phA[2], phA[3])),
                      hmax2(hmax2(phA[4], phA[5]), hmax2(phA[6], phA[7])));
    half2v mB = hmax2(hmax2(hmax2(phB[0], phB[1]), hmax2(phB[2], phB[3])),
                      hmax2(hmax2(phB[4], phB[5]), hmax2(phB[6], phB[7])));
    half2v mx2 = hmax2(mA, mB);
    int mi = __builtin_bit_cast(int, mx2);
    mx2 = hmax2(mx2, __builtin_bit_cast(half2v, __shfl_xor(mi, 16)));
    mi = __builtin_bit_cast(int, mx2);
    mx2 = hmax2(mx2, __builtin_bit_cast(half2v, __shfl_xor(mi, 32)));
    const float mxf = fmaxf((float)mx2[0], (float)mx2[1]);
    const bool up = mxf > mrow + 4.0f;
    const float mn = up ? mxf : mrow;
    const float alpha = up ? exp2f(mrow - mn) : 1.0f;
    mrow = mn;

    const _Float16 mnh = (_Float16)mn;
    half2v mn2; mn2[0] = mnh; mn2[1] = mnh;
    half2v peA[8], peB[8];
#pragma unroll
    for (int i = 0; i < 8; ++i) {
      peA[i] = __builtin_elementwise_exp2(phA[i] - mn2);
      peB[i] = __builtin_elementwise_exp2(phB[i] - mn2);
    }

    if (__ballot(up)) {
      float alr[4];
#pragma unroll
      for (int r = 0; r < 4; ++r) alr[r] = __shfl(alpha, quad * 4 + r);
#pragma unroll
      for (int jb = 0; jb < 4; ++jb)
#pragma unroll
        for (int r = 0; r < 4; ++r) o16[jb][r] *= alr[r];
#pragma unroll
      for (int r = 0; r < 4; ++r) lacc[r] *= alr[r];
    }

    half8 pA[2], pB[2];
#pragma unroll
    for (int t = 0; t < 2; ++t) {
      half4v loA = __builtin_shufflevector(peA[4 * t],     peA[4 * t + 1], 0, 1, 2, 3);
      half4v hiA = __builtin_shufflevector(peA[4 * t + 2], peA[4 * t + 3], 0, 1, 2, 3);
      pA[t] = __builtin_shufflevector(loA, hiA, 0, 1, 2, 3, 4, 5, 6, 7);
      half4v loB = __builtin_shufflevector(peB[4 * t],     peB[4 * t + 1], 0, 1, 2, 3);
      half4v hiB = __builtin_shufflevector(peB[4 * t + 2], peB[4 * t + 3], 0, 1, 2, 3);
      pB[t] = __builtin_shufflevector(loB, hiB, 0, 1, 2, 3, 4, 5, 6, 7);
    }

    __builtin_amdgcn_s_setprio(1);
    lacc = MFMA32(pA[0], ones8, lacc);
    lacc = MFMA32(pA[1], ones8, lacc);
    lacc = MFMA32(pB[0], ones8, lacc);
    lacc = MFMA32(pB[1], ones8, lacc);

#pragma unroll
    for (int jb = 0; jb < 4; ++jb) {
      const int vrow = (jb * 16 + l16) * 64;
#pragma unroll
      for (int t = 0; t < 2; ++t) {
        half8 vA = *(const half8*)&V0[vrow + (((2 * quad + t) ^ rx) * 8)];
        half8 vB = *(const half8*)&V1[vrow + (((2 * quad + t) ^ rx) * 8)];
        o16[jb] = MFMA32(pA[t], vA, o16[jb]);
        o16[jb] = MFMA32(pB[t], vB, o16[jb]);
      }
    }
    __builtin_amdgcn_s_setprio(0);
  };

  int cur = 0;
  for (int p = 0; p < 16; ++p) {     // 16 pairs of 64-row K/V tiles
    if (p + 1 < 16) stage(p + 1, cur ^ 1);   // DMA; flies under compute
    compute_pair(Kbuf[cur][0], Kbuf[cur][1], Vbuf[cur][0], Vbuf[cur][1]);
    __syncthreads();                         // drains vmcnt: next pair ready
    cur ^= 1;
  }

  float linv[4];
#pragma unroll
  for (int r = 0; r < 4; ++r) linv[r] = 1.0f / lacc[r];   // no shuffles needed
#pragma unroll
  for (int jb = 0; jb < 4; ++jb) {
#pragma unroll
    for (int r = 0; r < 4; ++r) {
      const int row = q0 + wave * 16 + quad * 4 + r;
      attnb[(size_t)(b * S + row) * INNER + h * HD + jb * 16 + l16] =
          (_Float16)(o16[jb][r] * linv[r]);
    }
  }
}

// ---------------------------------------------------------------------------
extern "C" void kernel_launch(void* const* d_in, const int* in_sizes, int n_in,
                              void* d_out, int out_size, void* d_ws, size_t ws_size,
                              hipStream_t stream) {
  const float* hs    = (const float*)d_in[0];
  const float* rot   = (const float*)d_in[1];
  const float* w_qkv = (const float*)d_in[2];
  const float* b_qkv = (const float*)d_in[3];
  const float* nqw   = (const float*)d_in[4];
  const float* nkw   = (const float*)d_in[5];
  const float* w_out = (const float*)d_in[6];
  const float* b_out = (const float*)d_in[7];
  const float* hks   = (const float*)d_in[8];
  const int*   octx  = (const int*)d_in[9];

  _Float16* attnb = (_Float16*)d_ws;                 // 0-8 MiB
  _Float16* wqkvT = attnb + (size_t)NTOK * DIM;      // 8-14 MiB
  _Float16* woutT = wqkvT + (size_t)QKVN * DIM;      // 14-16 MiB
  _Float16* qkvh  = woutT + (size_t)DIM * INNER;     // 16-40 MiB
  _Float16* q_h   = qkvh  + (size_t)NTOK * QKVN;     // 40-48 MiB
  _Float16* k_h   = q_h   + (size_t)B * NH * S * HD; // 48-56 MiB
  _Float16* vT    = k_h   + (size_t)B * NH * S * HD; // 56-64 MiB

  prep_all<<<1024, 256, 0, stream>>>(w_qkv, w_out, wqkvT, woutT);

  // R14: grid axes swapped — x = m-tiles (32), y = n-tiles.
  gemm_bt<128, true, true, true, _Float16><<<dim3(NTOK / 128, QKVN / 128), 256, 0, stream>>>(
      hs, wqkvT, b_qkv, qkvh, QKVN, DIM, vT);

  post_all<<<4096, 256, 0, stream>>>(qkvh, rot, nqw, nkw, hks, octx, q_h, k_h);

  attn_mfma<<<dim3(B * NH, S / 128), 512, 0, stream>>>(q_h, k_h, vT, attnb);

  gemm_bt<128, false, false, false, float><<<dim3(NTOK / 128, DIM / 128), 256, 0, stream>>>(
      attnb, woutT, b_out, (float*)d_out, DIM, INNER, nullptr);
}